// Round 30
// baseline (172.910 us; speedup 1.0000x reference)
//
#include <hip/hip_runtime.h>

typedef __attribute__((ext_vector_type(8))) short short8;     // 8 bf16 — MFMA A/B frag
typedef __attribute__((ext_vector_type(8))) unsigned short u16x8;
typedef __attribute__((ext_vector_type(4))) float f32x4;      // MFMA C/D frag
typedef __attribute__((ext_vector_type(4))) unsigned short u16x4;
typedef __attribute__((ext_vector_type(4))) float float4v;

#define MFMA(a, b, c) __builtin_amdgcn_mfma_f32_16x16x32_bf16(a, b, c, 0, 0, 0)
#define GLOAD_LDS16(gp, lp) __builtin_amdgcn_global_load_lds( \
    (const __attribute__((address_space(1))) void*)(gp),      \
    (__attribute__((address_space(3))) void*)(lp), 16, 0, 0)

__device__ __forceinline__ float bf2f(unsigned short u) {
    union { unsigned int i; float f; } v; v.i = ((unsigned int)u) << 16; return v.f;
}
__device__ __forceinline__ unsigned short f2bf(float f) {
    union { float f; unsigned int i; } v; v.f = f;
    unsigned int r = (v.i + 0x7FFFu + ((v.i >> 16) & 1u)) >> 16;
    return (unsigned short)r;
}
// cheap round-half-up bf16 (P tile only)
__device__ __forceinline__ unsigned short f2bfr(float f) {
    union { float f; unsigned int i; } v; v.f = f;
    return (unsigned short)((v.i + 0x8000u) >> 16);
}

// ---- mask compaction (r27-verified, unchanged) ----
__global__ __launch_bounds__(256)
void mask_scan(const int* __restrict__ mask, int* __restrict__ kidx, int* __restrict__ seff)
{
    constexpr int S = 2048;
    const int b = blockIdx.x;
    const int tid = threadIdx.x;
    __shared__ int ps[256];
    const int* m = mask + b * S;
    int loc[8], s = 0;
#pragma unroll
    for (int j = 0; j < 8; ++j) { loc[j] = m[tid * 8 + j]; s += loc[j]; }
#pragma unroll
    for (int j = 0; j < 8; ++j) kidx[b * S + tid * 8 + j] = b * S;   // safe default
    ps[tid] = s;
    __syncthreads();
    for (int off = 1; off < 256; off <<= 1) {
        int v = (tid >= off) ? ps[tid - off] : 0;
        __syncthreads();
        ps[tid] += v;
        __syncthreads();
    }
    int run = (tid > 0) ? ps[tid - 1] : 0;
#pragma unroll
    for (int j = 0; j < 8; ++j) {
        if (loc[j]) kidx[b * S + run] = b * S + tid * 8 + j;
        run += loc[j];
    }
    if (tid == 255) seff[b] = ps[255];
}

// ---- fused fp32->bf16 ingest (r29-verified, unchanged) ----
__global__ __launch_bounds__(256)
void ingest_all(const float* __restrict__ X,
                const float* __restrict__ Wq, const float* __restrict__ Wk,
                const float* __restrict__ Wv, const float* __restrict__ Wr,
                unsigned short* __restrict__ dst)
{
    constexpr int X4 = 2097152;          // NE/4
    constexpr int T4 = X4 + 4 * 262144;  // + 4*WE/4
    const int stride = gridDim.x * blockDim.x;
    for (int i = blockIdx.x * blockDim.x + threadIdx.x; i < T4; i += stride) {
        const float* src;
        int off;
        if (i < X4) { src = X; off = i; }
        else {
            int jj = i - X4;
            int ws = jj >> 18;
            off = jj & 0x3FFFF;
            src = (ws == 0) ? Wq : (ws == 1) ? Wk : (ws == 2) ? Wv : Wr;
        }
        float4v v = ((const float4v*)src)[off];
        u16x4 o;
#pragma unroll
        for (int j = 0; j < 4; ++j) o[j] = f2bf(v[j]);
        ((u16x4*)dst)[i] = o;
    }
}

// ---- Projection GEMM: m97 core + XCD 1D grid + UNIONED LDS (As/Bs | Ct bounce) ----
__global__ __launch_bounds__(256)
void proj_gemm(const unsigned short* __restrict__ X,
               const unsigned short* __restrict__ Wq, const unsigned short* __restrict__ Wk,
               const unsigned short* __restrict__ Wv, const unsigned short* __restrict__ Wr,
               unsigned short* __restrict__ Qo, unsigned short* __restrict__ Ko,
               unsigned short* __restrict__ Vo, unsigned short* __restrict__ Ro,
               const int* __restrict__ kidx, const int* __restrict__ seff)
{
    constexpr int Kd = 1024, N = 1024;
    // union: phase1 uses As(4096)+Bs(4096) shorts; epilogue reuses as Ct(128*136)
    __shared__ unsigned short smem[128 * 136];
    unsigned short* As = smem;
    unsigned short* Bs = smem + 4096;
    unsigned short* Ct = smem;
    const int tid = threadIdx.x;
    const int wid = tid >> 6, lane = tid & 63;
    const int g = lane >> 4, lr = lane & 15;
    const int bid = blockIdx.x;
    const int jx = bid & 7, t = bid >> 3;
    const int x = (t >> 5) * 8 + jx;
    const int c = t & 31;
    const int wsel = c >> 3;
    const int coltile = c & 7;
    const bool compact = (wsel == 1) || (wsel == 2);
    int rowBase;
    if (compact) {
        if (x >= 68) return;
        int b = x / 17, xt = x - b * 17;
        if (xt * 128 >= seff[b]) return;
        rowBase = b * 2048 + xt * 128;
    } else {
        if (x >= 64) return;
        rowBase = x * 128;
    }
    const unsigned short* W = (wsel == 0) ? Wq : (wsel == 1) ? Wk : (wsel == 2) ? Wv : Wr;
    unsigned short* O = (wsel == 0) ? Qo : (wsel == 1) ? Ko : (wsel == 2) ? Vo : Ro;
    const int colBase = coltile * 128;
    const int wm = wid >> 1, wn = wid & 1;

    f32x4 acc[4][4] = {};

    const int r0 = tid >> 2;
    const int c0 = (tid & 3) * 8;
    const int sA0 = compact ? kidx[rowBase + r0] : rowBase + r0;
    const int sA1 = compact ? kidx[rowBase + 64 + r0] : rowBase + 64 + r0;
    const unsigned short* ga0 = X + (size_t)sA0 * Kd + c0;
    const unsigned short* ga1 = X + (size_t)sA1 * Kd + c0;
    const unsigned short* gb0 = W + (size_t)(colBase + r0) * Kd + c0;
    const unsigned short* gb1 = W + (size_t)(colBase + 64 + r0) * Kd + c0;

    for (int kt = 0; kt < Kd; kt += 32) {
        if (kt) __syncthreads();
        GLOAD_LDS16(ga0 + kt, As + (size_t)tid * 8);
        GLOAD_LDS16(ga1 + kt, As + 2048 + (size_t)tid * 8);
        GLOAD_LDS16(gb0 + kt, Bs + (size_t)tid * 8);
        GLOAD_LDS16(gb1 + kt, Bs + 2048 + (size_t)tid * 8);
        asm volatile("s_waitcnt vmcnt(0)" ::: "memory");
        __syncthreads();
        short8 a[4], b[4];
#pragma unroll
        for (int mt = 0; mt < 4; ++mt)
            a[mt] = *reinterpret_cast<const short8*>(&As[(wm * 64 + mt * 16 + lr) * 32 + g * 8]);
#pragma unroll
        for (int nt = 0; nt < 4; ++nt)
            b[nt] = *reinterpret_cast<const short8*>(&Bs[(wn * 64 + nt * 16 + lr) * 32 + g * 8]);
#pragma unroll
        for (int mt = 0; mt < 4; ++mt)
#pragma unroll
            for (int nt = 0; nt < 4; ++nt)
                acc[mt][nt] = MFMA(a[mt], b[nt], acc[mt][nt]);
    }
    // epilogue: barrier (As/Bs now dead for ALL waves) -> Ct bounce -> coalesced stores
    __syncthreads();
#pragma unroll
    for (int mt = 0; mt < 4; ++mt)
#pragma unroll
        for (int nt = 0; nt < 4; ++nt)
#pragma unroll
            for (int r = 0; r < 4; ++r)
                Ct[(wm * 64 + mt * 16 + g * 4 + r) * 136 + wn * 64 + nt * 16 + lr] =
                    f2bf(acc[mt][nt][r]);
    __syncthreads();
#pragma unroll
    for (int pp = 0; pp < 8; ++pp) {
        int row = pp * 16 + (tid >> 4);
        int col = (tid & 15) * 8;
        u16x8 v8 = *reinterpret_cast<const u16x8*>(&Ct[row * 136 + col]);
        *reinterpret_cast<u16x8*>(&O[(size_t)(rowBase + row) * N + colBase + col]) = v8;
    }
}

// ---- MFMA flash attention over COMPACTED K/V (r27-verified, unchanged) ----
__global__ __launch_bounds__(512)
void attn_fwd(const unsigned short* __restrict__ Q, const unsigned short* __restrict__ Kb,
              const unsigned short* __restrict__ Vb, const int* __restrict__ seff,
              unsigned short* __restrict__ AO)
{
    constexpr int S = 2048, C = 1024, Dh = 64;
    constexpr int PST = 64;
    constexpr float SCL = 0.125f * 1.44269504f;
    constexpr float FM  = 16.0f;
    constexpr float MSK = -1.0e30f;
    __shared__ unsigned short Kt[2][64 * 64];
    __shared__ unsigned short Vt[2][64 * 64];
    __shared__ unsigned short Pt[8][16 * PST];
    const int tid = threadIdx.x;
    const int w = tid >> 6, lane = tid & 63;
    const int g = lane >> 4, lr = lane & 15;
    const int lin = blockIdx.x;
    const int hb = lin & 63, qt = lin >> 6;
    const int h = hb >> 2, b = hb & 3;
    const int qbase = qt * 128;
    const int qrow = qbase + w * 16 + lr;

    const int Sb = seff[b];
    const int ntiles = (Sb + 63) >> 6;

    const unsigned short* qptr = Q + (size_t)(b * S + qrow) * C + h * Dh;
    short8 qf[2];
    qf[0] = *reinterpret_cast<const short8*>(qptr + g * 8);
    qf[1] = *reinterpret_cast<const short8*>(qptr + 32 + g * 8);

    short8 ones;
#pragma unroll
    for (int j = 0; j < 8; ++j) ones[j] = (short)0x3F80;

    f32x4 o[4] = {};
    f32x4 lacc = {};

    const unsigned short* kg = Kb + (size_t)(b * S) * C + h * Dh;
    const unsigned short* vg = Vb + (size_t)(b * S) * C + h * Dh;

    const int kk0 = tid >> 3;
    const int kd0 = ((tid & 7) ^ (kk0 & 7)) * 8;
    const int vkey = tid >> 3;
    const int vsd = (tid & 7) * 8;

    short8 vv;
    GLOAD_LDS16(kg + (size_t)kk0 * C + kd0, &Kt[0][(size_t)tid * 8]);
    vv = *reinterpret_cast<const short8*>(vg + (size_t)vkey * C + vsd);
    asm volatile("s_waitcnt vmcnt(0)" ::: "memory");
    {
        const unsigned short* bb = (const unsigned short*)&vv;
#pragma unroll
        for (int j = 0; j < 8; ++j) {
            int d = vsd + j;
            int sw = (d & 7) ^ ((d >> 3) & 7);
            Vt[0][d * 64 + ((((vkey >> 3) ^ sw) << 3) | (vkey & 7))] = bb[j];
        }
    }
    __syncthreads();

    int cur = 0;
    for (int tt = 0; tt < ntiles; ++tt) {
        const int t = tt * 64;
        const bool hasNext = (tt + 1) < ntiles;
        if (hasNext) {
            const int tn = t + 64;
            GLOAD_LDS16(kg + (size_t)(tn + kk0) * C + kd0, &Kt[cur ^ 1][(size_t)tid * 8]);
            vv = *reinterpret_cast<const short8*>(vg + (size_t)(tn + vkey) * C + vsd);
        }
        f32x4 s[4];
        __builtin_amdgcn_s_setprio(1);
#pragma unroll
        for (int nt = 0; nt < 4; ++nt) {
            int key = nt * 16 + lr;
            f32x4 a = {};
#pragma unroll
            for (int c = 0; c < 2; ++c) {
                int dd = c * 32 + g * 8;
                short8 kf = *reinterpret_cast<const short8*>(
                    &Kt[cur][key * 64 + (((dd >> 3) ^ (key & 7)) << 3)]);
                a = MFMA(qf[c], kf, a);
            }
            s[nt] = a;
        }
        __builtin_amdgcn_s_setprio(0);
        float madd[4];
#pragma unroll
        for (int nt = 0; nt < 4; ++nt)
            madd[nt] = ((t + nt * 16 + lr) < Sb) ? -FM : MSK;
        unsigned short* Pw = Pt[w];
#pragma unroll
        for (int nt = 0; nt < 4; ++nt) {
            int k = nt * 16 + lr;
#pragma unroll
            for (int r = 0; r < 4; ++r) {
                float p = __builtin_amdgcn_exp2f(s[nt][r] * SCL + madd[nt]);
                int row = g * 4 + r;
                Pw[row * PST + ((((k >> 3) ^ (row & 7)) << 3) | (k & 7))] = f2bfr(p);
            }
        }
        asm volatile("s_waitcnt lgkmcnt(0)" ::: "memory");
        __builtin_amdgcn_sched_barrier(0);
        short8 pf[2];
#pragma unroll
        for (int hh = 0; hh < 2; ++hh) {
            int kk = hh * 32 + g * 8;
            pf[hh] = *reinterpret_cast<const short8*>(
                &Pw[lr * PST + (((kk >> 3) ^ (lr & 7)) << 3)]);
        }
        __builtin_amdgcn_s_setprio(1);
        lacc = MFMA(pf[0], ones, lacc);
        lacc = MFMA(pf[1], ones, lacc);
#pragma unroll
        for (int dt = 0; dt < 4; ++dt) {
            int d = dt * 16 + lr;
#pragma unroll
            for (int hh = 0; hh < 2; ++hh) {
                int kk = hh * 32 + g * 8;
                short8 vf = *reinterpret_cast<const short8*>(
                    &Vt[cur][d * 64 + ((((kk >> 3) ^ (d & 7) ^ ((d >> 3) & 7)) << 3))]);
                o[dt] = MFMA(pf[hh], vf, o[dt]);
            }
        }
        __builtin_amdgcn_s_setprio(0);
        if (hasNext) {
            asm volatile("s_waitcnt vmcnt(0)" ::: "memory");
            const unsigned short* bb = (const unsigned short*)&vv;
            unsigned short* Vn = Vt[cur ^ 1];
#pragma unroll
            for (int j = 0; j < 8; ++j) {
                int d = vsd + j;
                int sw = (d & 7) ^ ((d >> 3) & 7);
                Vn[d * 64 + ((((vkey >> 3) ^ sw) << 3) | (vkey & 7))] = bb[j];
            }
        }
        __syncthreads();
        cur ^= 1;
    }
#pragma unroll
    for (int dt = 0; dt < 4; ++dt)
#pragma unroll
        for (int r = 0; r < 4; ++r) {
            int row = qbase + w * 16 + g * 4 + r;
            int col = h * Dh + dt * 16 + lr;
            AO[(size_t)(b * S + row) * C + col] = f2bf(o[dt][r] / lacc[r]);
        }
}

// ---- Epilogue: LN with wave-shuffle reduction (restored fast path) ----
__global__ __launch_bounds__(256)
void ln_ep(const unsigned short* __restrict__ AO, const unsigned short* __restrict__ R,
           const float* __restrict__ gamma, const float* __restrict__ beta,
           float* __restrict__ out)
{
    constexpr int C = 1024;
    const int row = blockIdx.x;
    const int tid = threadIdx.x;
    __shared__ float red[4][2];

    float v[4]; float sum = 0.f, ss = 0.f;
    u16x4 av = *reinterpret_cast<const u16x4*>(AO + (size_t)row * C + tid * 4);
    u16x4 rv = *reinterpret_cast<const u16x4*>(R + (size_t)row * C + tid * 4);
#pragma unroll
    for (int i = 0; i < 4; ++i) {
        v[i] = fmaxf(0.f, bf2f(av[i]) + bf2f(rv[i]));
        sum += v[i]; ss += v[i] * v[i];
    }
#pragma unroll
    for (int off = 1; off < 64; off <<= 1) {
        sum += __shfl_xor(sum, off, 64);
        ss += __shfl_xor(ss, off, 64);
    }
    int w = tid >> 6;
    if ((tid & 63) == 0) { red[w][0] = sum; red[w][1] = ss; }
    __syncthreads();
    sum = red[0][0] + red[1][0] + red[2][0] + red[3][0];
    ss = red[0][1] + red[1][1] + red[2][1] + red[3][1];
    float mu = sum * (1.f / C);
    float var = ss * (1.f / C) - mu * mu;
    float rstd = rsqrtf(var + 1e-5f);
    float4v g4 = *reinterpret_cast<const float4v*>(gamma + tid * 4);
    float4v b4 = *reinterpret_cast<const float4v*>(beta + tid * 4);
    float4v ov;
#pragma unroll
    for (int i = 0; i < 4; ++i)
        ov[i] = (v[i] - mu) * rstd * g4[i] + b4[i];
    *reinterpret_cast<float4v*>(out + (size_t)row * C + tid * 4) = ov;
}

extern "C" void kernel_launch(void* const* d_in, const int* in_sizes, int n_in,
                              void* d_out, int out_size, void* d_ws, size_t ws_size,
                              hipStream_t stream)
{
    const float* X = (const float*)d_in[0];
    const int* mask = (const int*)d_in[1];
    const float* Wq = (const float*)d_in[2];
    const float* Wk = (const float*)d_in[3];
    const float* Wv = (const float*)d_in[4];
    const float* Wr = (const float*)d_in[5];
    const float* Gm = (const float*)d_in[6];
    const float* Bt = (const float*)d_in[7];
    float* out = (float*)d_out;

    const size_t NE = (size_t)8192 * 1024;
    const size_t WE = (size_t)1024 * 1024;
    unsigned short* p = (unsigned short*)d_ws;
    unsigned short* Xb = p;   p += NE;
    unsigned short* Wqb = p;  p += WE;
    unsigned short* Wkb = p;  p += WE;
    unsigned short* Wvb = p;  p += WE;
    unsigned short* Wrb = p;  p += WE;
    unsigned short* Qb = p;   p += NE;
    unsigned short* Kb = p;   p += NE;
    unsigned short* Vb = p;   p += NE;
    unsigned short* Rb = p;   p += NE;
    int* kidx = (int*)p;      p += 8192 * 2;
    int* seff = (int*)p;      p += 8;
    unsigned short* AO = Xb;  // alias: X dead after proj_gemm

    mask_scan<<<dim3(4), 256, 0, stream>>>(mask, kidx, seff);
    ingest_all<<<dim3(2048), 256, 0, stream>>>(X, Wq, Wk, Wv, Wr, Xb);

    proj_gemm<<<dim3(2304), 256, 0, stream>>>(Xb, Wqb, Wkb, Wvb, Wrb,
                                              Qb, Kb, Vb, Rb, kidx, seff);
    attn_fwd<<<dim3(1024), 512, 0, stream>>>(Qb, Kb, Vb, seff, AO);
    ln_ep<<<dim3(8192), 256, 0, stream>>>(AO, Rb, Gm, Bt, out);
}

// Round 31
// 165.118 us; speedup vs baseline: 1.0472x; 1.0472x over previous
//
#include <hip/hip_runtime.h>

typedef __attribute__((ext_vector_type(8))) short short8;     // 8 bf16 — MFMA A/B frag
typedef __attribute__((ext_vector_type(8))) unsigned short u16x8;
typedef __attribute__((ext_vector_type(4))) float f32x4;      // MFMA C/D frag
typedef __attribute__((ext_vector_type(4))) unsigned short u16x4;
typedef __attribute__((ext_vector_type(4))) float float4v;

#define MFMA(a, b, c) __builtin_amdgcn_mfma_f32_16x16x32_bf16(a, b, c, 0, 0, 0)
#define GLOAD_LDS16(gp, lp) __builtin_amdgcn_global_load_lds( \
    (const __attribute__((address_space(1))) void*)(gp),      \
    (__attribute__((address_space(3))) void*)(lp), 16, 0, 0)

__device__ __forceinline__ float bf2f(unsigned short u) {
    union { unsigned int i; float f; } v; v.i = ((unsigned int)u) << 16; return v.f;
}
__device__ __forceinline__ unsigned short f2bf(float f) {
    union { float f; unsigned int i; } v; v.f = f;
    unsigned int r = (v.i + 0x7FFFu + ((v.i >> 16) & 1u)) >> 16;
    return (unsigned short)r;
}
// cheap round-half-up bf16 (P tile only)
__device__ __forceinline__ unsigned short f2bfr(float f) {
    union { float f; unsigned int i; } v; v.f = f;
    return (unsigned short)((v.i + 0x8000u) >> 16);
}

// ---- mask compaction (r27-verified, unchanged) ----
__global__ __launch_bounds__(256)
void mask_scan(const int* __restrict__ mask, int* __restrict__ kidx, int* __restrict__ seff)
{
    constexpr int S = 2048;
    const int b = blockIdx.x;
    const int tid = threadIdx.x;
    __shared__ int ps[256];
    const int* m = mask + b * S;
    int loc[8], s = 0;
#pragma unroll
    for (int j = 0; j < 8; ++j) { loc[j] = m[tid * 8 + j]; s += loc[j]; }
#pragma unroll
    for (int j = 0; j < 8; ++j) kidx[b * S + tid * 8 + j] = b * S;   // safe default
    ps[tid] = s;
    __syncthreads();
    for (int off = 1; off < 256; off <<= 1) {
        int v = (tid >= off) ? ps[tid - off] : 0;
        __syncthreads();
        ps[tid] += v;
        __syncthreads();
    }
    int run = (tid > 0) ? ps[tid - 1] : 0;
#pragma unroll
    for (int j = 0; j < 8; ++j) {
        if (loc[j]) kidx[b * S + run] = b * S + tid * 8 + j;
        run += loc[j];
    }
    if (tid == 255) seff[b] = ps[255];
}

// ---- fused fp32->bf16 ingest (r29-verified, unchanged) ----
__global__ __launch_bounds__(256)
void ingest_all(const float* __restrict__ X,
                const float* __restrict__ Wq, const float* __restrict__ Wk,
                const float* __restrict__ Wv, const float* __restrict__ Wr,
                unsigned short* __restrict__ dst)
{
    constexpr int X4 = 2097152;          // NE/4
    constexpr int T4 = X4 + 4 * 262144;  // + 4*WE/4
    const int stride = gridDim.x * blockDim.x;
    for (int i = blockIdx.x * blockDim.x + threadIdx.x; i < T4; i += stride) {
        const float* src;
        int off;
        if (i < X4) { src = X; off = i; }
        else {
            int jj = i - X4;
            int ws = jj >> 18;
            off = jj & 0x3FFFF;
            src = (ws == 0) ? Wq : (ws == 1) ? Wk : (ws == 2) ? Wv : Wr;
        }
        float4v v = ((const float4v*)src)[off];
        u16x4 o;
#pragma unroll
        for (int j = 0; j < 4; ++j) o[j] = f2bf(v[j]);
        ((u16x4*)dst)[i] = o;
    }
}

// ---- Projection GEMM: 128^2 tile, BK=64 (16 MFMA per barrier-pair), XCD 1D grid,
//      XOR-swizzled LDS (linear gload_lds dest + pre-swizzled source), Ct-union epilogue ----
__global__ __launch_bounds__(256)
void proj_gemm(const unsigned short* __restrict__ X,
               const unsigned short* __restrict__ Wq, const unsigned short* __restrict__ Wk,
               const unsigned short* __restrict__ Wv, const unsigned short* __restrict__ Wr,
               unsigned short* __restrict__ Qo, unsigned short* __restrict__ Ko,
               unsigned short* __restrict__ Vo, unsigned short* __restrict__ Ro,
               const int* __restrict__ kidx, const int* __restrict__ seff)
{
    constexpr int Kd = 1024, N = 1024;
    // union: phase1 As(128*64)+Bs(128*64) shorts = 32KB; epilogue Ct(128*136) = 34.8KB
    __shared__ unsigned short smem[128 * 136];
    unsigned short* As = smem;
    unsigned short* Bs = smem + 8192;
    unsigned short* Ct = smem;
    const int tid = threadIdx.x;
    const int wid = tid >> 6, lane = tid & 63;
    const int g = lane >> 4, lr = lane & 15;
    const int bid = blockIdx.x;
    const int jx = bid & 7, t = bid >> 3;
    const int x = (t >> 5) * 8 + jx;
    const int c = t & 31;
    const int wsel = c >> 3;
    const int coltile = c & 7;
    const bool compact = (wsel == 1) || (wsel == 2);
    int rowBase;
    if (compact) {
        if (x >= 68) return;
        int b = x / 17, xt = x - b * 17;
        if (xt * 128 >= seff[b]) return;
        rowBase = b * 2048 + xt * 128;
    } else {
        if (x >= 64) return;
        rowBase = x * 128;
    }
    const unsigned short* W = (wsel == 0) ? Wq : (wsel == 1) ? Wk : (wsel == 2) ? Wv : Wr;
    unsigned short* O = (wsel == 0) ? Qo : (wsel == 1) ? Ko : (wsel == 2) ? Vo : Ro;
    const int colBase = coltile * 128;
    const int wm = wid >> 1, wn = wid & 1;

    f32x4 acc[4][4] = {};

    // staging: 1024 chunks per matrix, 4 per thread. chunk n: row=n>>3, colblk=(n&7)^(row&7)
    const unsigned short* srcA[4];
    const unsigned short* srcB[4];
#pragma unroll
    for (int i = 0; i < 4; ++i) {
        int n = tid + 256 * i;
        int r = n >> 3;
        int cb = (n & 7) ^ (r & 7);
        int sA = compact ? kidx[rowBase + r] : rowBase + r;
        srcA[i] = X + (size_t)sA * Kd + cb * 8;
        srcB[i] = W + (size_t)(colBase + r) * Kd + cb * 8;
    }

    for (int kt = 0; kt < Kd; kt += 64) {
        if (kt) __syncthreads();
#pragma unroll
        for (int i = 0; i < 4; ++i)
            GLOAD_LDS16(srcA[i] + kt, As + (size_t)(tid + 256 * i) * 8);
#pragma unroll
        for (int i = 0; i < 4; ++i)
            GLOAD_LDS16(srcB[i] + kt, Bs + (size_t)(tid + 256 * i) * 8);
        asm volatile("s_waitcnt vmcnt(0)" ::: "memory");
        __syncthreads();
#pragma unroll
        for (int kkb = 0; kkb < 8; kkb += 4) {      // two K=32 halves
            short8 a[4], b[4];
#pragma unroll
            for (int mt = 0; mt < 4; ++mt) {
                int row = wm * 64 + mt * 16 + lr;
                a[mt] = *reinterpret_cast<const short8*>(
                    &As[row * 64 + (((g + kkb) ^ (lr & 7)) << 3)]);
            }
#pragma unroll
            for (int nt = 0; nt < 4; ++nt) {
                int row = wn * 64 + nt * 16 + lr;
                b[nt] = *reinterpret_cast<const short8*>(
                    &Bs[row * 64 + (((g + kkb) ^ (lr & 7)) << 3)]);
            }
#pragma unroll
            for (int mt = 0; mt < 4; ++mt)
#pragma unroll
                for (int nt = 0; nt < 4; ++nt)
                    acc[mt][nt] = MFMA(a[mt], b[nt], acc[mt][nt]);
        }
    }
    // epilogue: barrier (As/Bs dead) -> Ct bounce -> coalesced u16x8 stores
    __syncthreads();
#pragma unroll
    for (int mt = 0; mt < 4; ++mt)
#pragma unroll
        for (int nt = 0; nt < 4; ++nt)
#pragma unroll
            for (int r = 0; r < 4; ++r)
                Ct[(wm * 64 + mt * 16 + g * 4 + r) * 136 + wn * 64 + nt * 16 + lr] =
                    f2bf(acc[mt][nt][r]);
    __syncthreads();
#pragma unroll
    for (int pp = 0; pp < 8; ++pp) {
        int row = pp * 16 + (tid >> 4);
        int col = (tid & 15) * 8;
        u16x8 v8 = *reinterpret_cast<const u16x8*>(&Ct[row * 136 + col]);
        *reinterpret_cast<u16x8*>(&O[(size_t)(rowBase + row) * N + colBase + col]) = v8;
    }
}

// ---- MFMA flash attention over COMPACTED K/V (r27-verified, unchanged) ----
__global__ __launch_bounds__(512)
void attn_fwd(const unsigned short* __restrict__ Q, const unsigned short* __restrict__ Kb,
              const unsigned short* __restrict__ Vb, const int* __restrict__ seff,
              unsigned short* __restrict__ AO)
{
    constexpr int S = 2048, C = 1024, Dh = 64;
    constexpr int PST = 64;
    constexpr float SCL = 0.125f * 1.44269504f;
    constexpr float FM  = 16.0f;
    constexpr float MSK = -1.0e30f;
    __shared__ unsigned short Kt[2][64 * 64];
    __shared__ unsigned short Vt[2][64 * 64];
    __shared__ unsigned short Pt[8][16 * PST];
    const int tid = threadIdx.x;
    const int w = tid >> 6, lane = tid & 63;
    const int g = lane >> 4, lr = lane & 15;
    const int lin = blockIdx.x;
    const int hb = lin & 63, qt = lin >> 6;
    const int h = hb >> 2, b = hb & 3;
    const int qbase = qt * 128;
    const int qrow = qbase + w * 16 + lr;

    const int Sb = seff[b];
    const int ntiles = (Sb + 63) >> 6;

    const unsigned short* qptr = Q + (size_t)(b * S + qrow) * C + h * Dh;
    short8 qf[2];
    qf[0] = *reinterpret_cast<const short8*>(qptr + g * 8);
    qf[1] = *reinterpret_cast<const short8*>(qptr + 32 + g * 8);

    short8 ones;
#pragma unroll
    for (int j = 0; j < 8; ++j) ones[j] = (short)0x3F80;

    f32x4 o[4] = {};
    f32x4 lacc = {};

    const unsigned short* kg = Kb + (size_t)(b * S) * C + h * Dh;
    const unsigned short* vg = Vb + (size_t)(b * S) * C + h * Dh;

    const int kk0 = tid >> 3;
    const int kd0 = ((tid & 7) ^ (kk0 & 7)) * 8;
    const int vkey = tid >> 3;
    const int vsd = (tid & 7) * 8;

    short8 vv;
    GLOAD_LDS16(kg + (size_t)kk0 * C + kd0, &Kt[0][(size_t)tid * 8]);
    vv = *reinterpret_cast<const short8*>(vg + (size_t)vkey * C + vsd);
    asm volatile("s_waitcnt vmcnt(0)" ::: "memory");
    {
        const unsigned short* bb = (const unsigned short*)&vv;
#pragma unroll
        for (int j = 0; j < 8; ++j) {
            int d = vsd + j;
            int sw = (d & 7) ^ ((d >> 3) & 7);
            Vt[0][d * 64 + ((((vkey >> 3) ^ sw) << 3) | (vkey & 7))] = bb[j];
        }
    }
    __syncthreads();

    int cur = 0;
    for (int tt = 0; tt < ntiles; ++tt) {
        const int t = tt * 64;
        const bool hasNext = (tt + 1) < ntiles;
        if (hasNext) {
            const int tn = t + 64;
            GLOAD_LDS16(kg + (size_t)(tn + kk0) * C + kd0, &Kt[cur ^ 1][(size_t)tid * 8]);
            vv = *reinterpret_cast<const short8*>(vg + (size_t)(tn + vkey) * C + vsd);
        }
        f32x4 s[4];
        __builtin_amdgcn_s_setprio(1);
#pragma unroll
        for (int nt = 0; nt < 4; ++nt) {
            int key = nt * 16 + lr;
            f32x4 a = {};
#pragma unroll
            for (int c = 0; c < 2; ++c) {
                int dd = c * 32 + g * 8;
                short8 kf = *reinterpret_cast<const short8*>(
                    &Kt[cur][key * 64 + (((dd >> 3) ^ (key & 7)) << 3)]);
                a = MFMA(qf[c], kf, a);
            }
            s[nt] = a;
        }
        __builtin_amdgcn_s_setprio(0);
        float madd[4];
#pragma unroll
        for (int nt = 0; nt < 4; ++nt)
            madd[nt] = ((t + nt * 16 + lr) < Sb) ? -FM : MSK;
        unsigned short* Pw = Pt[w];
#pragma unroll
        for (int nt = 0; nt < 4; ++nt) {
            int k = nt * 16 + lr;
#pragma unroll
            for (int r = 0; r < 4; ++r) {
                float p = __builtin_amdgcn_exp2f(s[nt][r] * SCL + madd[nt]);
                int row = g * 4 + r;
                Pw[row * PST + ((((k >> 3) ^ (row & 7)) << 3) | (k & 7))] = f2bfr(p);
            }
        }
        asm volatile("s_waitcnt lgkmcnt(0)" ::: "memory");
        __builtin_amdgcn_sched_barrier(0);
        short8 pf[2];
#pragma unroll
        for (int hh = 0; hh < 2; ++hh) {
            int kk = hh * 32 + g * 8;
            pf[hh] = *reinterpret_cast<const short8*>(
                &Pw[lr * PST + (((kk >> 3) ^ (lr & 7)) << 3)]);
        }
        __builtin_amdgcn_s_setprio(1);
        lacc = MFMA(pf[0], ones, lacc);
        lacc = MFMA(pf[1], ones, lacc);
#pragma unroll
        for (int dt = 0; dt < 4; ++dt) {
            int d = dt * 16 + lr;
#pragma unroll
            for (int hh = 0; hh < 2; ++hh) {
                int kk = hh * 32 + g * 8;
                short8 vf = *reinterpret_cast<const short8*>(
                    &Vt[cur][d * 64 + ((((kk >> 3) ^ (d & 7) ^ ((d >> 3) & 7)) << 3))]);
                o[dt] = MFMA(pf[hh], vf, o[dt]);
            }
        }
        __builtin_amdgcn_s_setprio(0);
        if (hasNext) {
            asm volatile("s_waitcnt vmcnt(0)" ::: "memory");
            const unsigned short* bb = (const unsigned short*)&vv;
            unsigned short* Vn = Vt[cur ^ 1];
#pragma unroll
            for (int j = 0; j < 8; ++j) {
                int d = vsd + j;
                int sw = (d & 7) ^ ((d >> 3) & 7);
                Vn[d * 64 + ((((vkey >> 3) ^ sw) << 3) | (vkey & 7))] = bb[j];
            }
        }
        __syncthreads();
        cur ^= 1;
    }
#pragma unroll
    for (int dt = 0; dt < 4; ++dt)
#pragma unroll
        for (int r = 0; r < 4; ++r) {
            int row = qbase + w * 16 + g * 4 + r;
            int col = h * Dh + dt * 16 + lr;
            AO[(size_t)(b * S + row) * C + col] = f2bf(o[dt][r] / lacc[r]);
        }
}

// ---- Epilogue: LN with wave-shuffle reduction (r30-verified, unchanged) ----
__global__ __launch_bounds__(256)
void ln_ep(const unsigned short* __restrict__ AO, const unsigned short* __restrict__ R,
           const float* __restrict__ gamma, const float* __restrict__ beta,
           float* __restrict__ out)
{
    constexpr int C = 1024;
    const int row = blockIdx.x;
    const int tid = threadIdx.x;
    __shared__ float red[4][2];

    float v[4]; float sum = 0.f, ss = 0.f;
    u16x4 av = *reinterpret_cast<const u16x4*>(AO + (size_t)row * C + tid * 4);
    u16x4 rv = *reinterpret_cast<const u16x4*>(R + (size_t)row * C + tid * 4);
#pragma unroll
    for (int i = 0; i < 4; ++i) {
        v[i] = fmaxf(0.f, bf2f(av[i]) + bf2f(rv[i]));
        sum += v[i]; ss += v[i] * v[i];
    }
#pragma unroll
    for (int off = 1; off < 64; off <<= 1) {
        sum += __shfl_xor(sum, off, 64);
        ss += __shfl_xor(ss, off, 64);
    }
    int w = tid >> 6;
    if ((tid & 63) == 0) { red[w][0] = sum; red[w][1] = ss; }
    __syncthreads();
    sum = red[0][0] + red[1][0] + red[2][0] + red[3][0];
    ss = red[0][1] + red[1][1] + red[2][1] + red[3][1];
    float mu = sum * (1.f / C);
    float var = ss * (1.f / C) - mu * mu;
    float rstd = rsqrtf(var + 1e-5f);
    float4v g4 = *reinterpret_cast<const float4v*>(gamma + tid * 4);
    float4v b4 = *reinterpret_cast<const float4v*>(beta + tid * 4);
    float4v ov;
#pragma unroll
    for (int i = 0; i < 4; ++i)
        ov[i] = (v[i] - mu) * rstd * g4[i] + b4[i];
    *reinterpret_cast<float4v*>(out + (size_t)row * C + tid * 4) = ov;
}

extern "C" void kernel_launch(void* const* d_in, const int* in_sizes, int n_in,
                              void* d_out, int out_size, void* d_ws, size_t ws_size,
                              hipStream_t stream)
{
    const float* X = (const float*)d_in[0];
    const int* mask = (const int*)d_in[1];
    const float* Wq = (const float*)d_in[2];
    const float* Wk = (const float*)d_in[3];
    const float* Wv = (const float*)d_in[4];
    const float* Wr = (const float*)d_in[5];
    const float* Gm = (const float*)d_in[6];
    const float* Bt = (const float*)d_in[7];
    float* out = (float*)d_out;

    const size_t NE = (size_t)8192 * 1024;
    const size_t WE = (size_t)1024 * 1024;
    unsigned short* p = (unsigned short*)d_ws;
    unsigned short* Xb = p;   p += NE;
    unsigned short* Wqb = p;  p += WE;
    unsigned short* Wkb = p;  p += WE;
    unsigned short* Wvb = p;  p += WE;
    unsigned short* Wrb = p;  p += WE;
    unsigned short* Qb = p;   p += NE;
    unsigned short* Kb = p;   p += NE;
    unsigned short* Vb = p;   p += NE;
    unsigned short* Rb = p;   p += NE;
    int* kidx = (int*)p;      p += 8192 * 2;
    int* seff = (int*)p;      p += 8;
    unsigned short* AO = Xb;  // alias: X dead after proj_gemm

    mask_scan<<<dim3(4), 256, 0, stream>>>(mask, kidx, seff);
    ingest_all<<<dim3(2048), 256, 0, stream>>>(X, Wq, Wk, Wv, Wr, Xb);

    proj_gemm<<<dim3(2304), 256, 0, stream>>>(Xb, Wqb, Wkb, Wvb, Wrb,
                                              Qb, Kb, Vb, Rb, kidx, seff);
    attn_fwd<<<dim3(1024), 512, 0, stream>>>(Qb, Kb, Vb, seff, AO);
    ln_ep<<<dim3(8192), 256, 0, stream>>>(AO, Rb, Gm, Bt, out);
}

// Round 32
// 162.047 us; speedup vs baseline: 1.0670x; 1.0190x over previous
//
#include <hip/hip_runtime.h>

typedef __attribute__((ext_vector_type(8))) short short8;     // 8 bf16 — MFMA A/B frag
typedef __attribute__((ext_vector_type(8))) unsigned short u16x8;
typedef __attribute__((ext_vector_type(4))) float f32x4;      // MFMA C/D frag
typedef __attribute__((ext_vector_type(4))) unsigned short u16x4;
typedef __attribute__((ext_vector_type(4))) float float4v;

#define MFMA(a, b, c) __builtin_amdgcn_mfma_f32_16x16x32_bf16(a, b, c, 0, 0, 0)
#define GLOAD_LDS16(gp, lp) __builtin_amdgcn_global_load_lds( \
    (const __attribute__((address_space(1))) void*)(gp),      \
    (__attribute__((address_space(3))) void*)(lp), 16, 0, 0)

__device__ __forceinline__ float bf2f(unsigned short u) {
    union { unsigned int i; float f; } v; v.i = ((unsigned int)u) << 16; return v.f;
}
__device__ __forceinline__ unsigned short f2bf(float f) {
    union { float f; unsigned int i; } v; v.f = f;
    unsigned int r = (v.i + 0x7FFFu + ((v.i >> 16) & 1u)) >> 16;
    return (unsigned short)r;
}
// cheap round-half-up bf16 (P tile only)
__device__ __forceinline__ unsigned short f2bfr(float f) {
    union { float f; unsigned int i; } v; v.f = f;
    return (unsigned short)((v.i + 0x8000u) >> 16);
}

// ---- mask compaction (r27-verified, unchanged) ----
__global__ __launch_bounds__(256)
void mask_scan(const int* __restrict__ mask, int* __restrict__ kidx, int* __restrict__ seff)
{
    constexpr int S = 2048;
    const int b = blockIdx.x;
    const int tid = threadIdx.x;
    __shared__ int ps[256];
    const int* m = mask + b * S;
    int loc[8], s = 0;
#pragma unroll
    for (int j = 0; j < 8; ++j) { loc[j] = m[tid * 8 + j]; s += loc[j]; }
#pragma unroll
    for (int j = 0; j < 8; ++j) kidx[b * S + tid * 8 + j] = b * S;   // safe default
    ps[tid] = s;
    __syncthreads();
    for (int off = 1; off < 256; off <<= 1) {
        int v = (tid >= off) ? ps[tid - off] : 0;
        __syncthreads();
        ps[tid] += v;
        __syncthreads();
    }
    int run = (tid > 0) ? ps[tid - 1] : 0;
#pragma unroll
    for (int j = 0; j < 8; ++j) {
        if (loc[j]) kidx[b * S + run] = b * S + tid * 8 + j;
        run += loc[j];
    }
    if (tid == 255) seff[b] = ps[255];
}

// ---- fused fp32->bf16 ingest (r29-verified, unchanged) ----
__global__ __launch_bounds__(256)
void ingest_all(const float* __restrict__ X,
                const float* __restrict__ Wq, const float* __restrict__ Wk,
                const float* __restrict__ Wv, const float* __restrict__ Wr,
                unsigned short* __restrict__ dst)
{
    constexpr int X4 = 2097152;          // NE/4
    constexpr int T4 = X4 + 4 * 262144;  // + 4*WE/4
    const int stride = gridDim.x * blockDim.x;
    for (int i = blockIdx.x * blockDim.x + threadIdx.x; i < T4; i += stride) {
        const float* src;
        int off;
        if (i < X4) { src = X; off = i; }
        else {
            int jj = i - X4;
            int ws = jj >> 18;
            off = jj & 0x3FFFF;
            src = (ws == 0) ? Wq : (ws == 1) ? Wk : (ws == 2) ? Wv : Wr;
        }
        float4v v = ((const float4v*)src)[off];
        u16x4 o;
#pragma unroll
        for (int j = 0; j < 4; ++j) o[j] = f2bf(v[j]);
        ((u16x4*)dst)[i] = o;
    }
}

// ---- Projection GEMM (r31 core, BK=64). wsel==2 (V) stores TRANSPOSED:
//      VT[b][feature][token] so attention can DMA V tiles directly. ----
__global__ __launch_bounds__(256)
void proj_gemm(const unsigned short* __restrict__ X,
               const unsigned short* __restrict__ Wq, const unsigned short* __restrict__ Wk,
               const unsigned short* __restrict__ Wv, const unsigned short* __restrict__ Wr,
               unsigned short* __restrict__ Qo, unsigned short* __restrict__ Ko,
               unsigned short* __restrict__ VT, unsigned short* __restrict__ Ro,
               const int* __restrict__ kidx, const int* __restrict__ seff)
{
    constexpr int Kd = 1024, N = 1024;
    __shared__ unsigned short smem[128 * 136];
    unsigned short* As = smem;
    unsigned short* Bs = smem + 8192;
    unsigned short* Ct = smem;
    const int tid = threadIdx.x;
    const int wid = tid >> 6, lane = tid & 63;
    const int g = lane >> 4, lr = lane & 15;
    const int bid = blockIdx.x;
    const int jx = bid & 7, t = bid >> 3;
    const int x = (t >> 5) * 8 + jx;
    const int c = t & 31;
    const int wsel = c >> 3;
    const int coltile = c & 7;
    const bool compact = (wsel == 1) || (wsel == 2);
    int rowBase;
    if (compact) {
        if (x >= 68) return;
        int b = x / 17, xt = x - b * 17;
        if (xt * 128 >= seff[b]) return;
        rowBase = b * 2048 + xt * 128;
    } else {
        if (x >= 64) return;
        rowBase = x * 128;
    }
    const unsigned short* W = (wsel == 0) ? Wq : (wsel == 1) ? Wk : (wsel == 2) ? Wv : Wr;
    unsigned short* O = (wsel == 0) ? Qo : (wsel == 1) ? Ko : (wsel == 2) ? VT : Ro;
    const int colBase = coltile * 128;
    const int wm = wid >> 1, wn = wid & 1;

    f32x4 acc[4][4] = {};

    const unsigned short* srcA[4];
    const unsigned short* srcB[4];
#pragma unroll
    for (int i = 0; i < 4; ++i) {
        int n = tid + 256 * i;
        int r = n >> 3;
        int cb = (n & 7) ^ (r & 7);
        int sA = compact ? kidx[rowBase + r] : rowBase + r;
        srcA[i] = X + (size_t)sA * Kd + cb * 8;
        srcB[i] = W + (size_t)(colBase + r) * Kd + cb * 8;
    }

    for (int kt = 0; kt < Kd; kt += 64) {
        if (kt) __syncthreads();
#pragma unroll
        for (int i = 0; i < 4; ++i)
            GLOAD_LDS16(srcA[i] + kt, As + (size_t)(tid + 256 * i) * 8);
#pragma unroll
        for (int i = 0; i < 4; ++i)
            GLOAD_LDS16(srcB[i] + kt, Bs + (size_t)(tid + 256 * i) * 8);
        asm volatile("s_waitcnt vmcnt(0)" ::: "memory");
        __syncthreads();
#pragma unroll
        for (int kkb = 0; kkb < 8; kkb += 4) {      // two K=32 halves
            short8 a[4], b[4];
#pragma unroll
            for (int mt = 0; mt < 4; ++mt) {
                int row = wm * 64 + mt * 16 + lr;
                a[mt] = *reinterpret_cast<const short8*>(
                    &As[row * 64 + (((g + kkb) ^ (lr & 7)) << 3)]);
            }
#pragma unroll
            for (int nt = 0; nt < 4; ++nt) {
                int row = wn * 64 + nt * 16 + lr;
                b[nt] = *reinterpret_cast<const short8*>(
                    &Bs[row * 64 + (((g + kkb) ^ (lr & 7)) << 3)]);
            }
#pragma unroll
            for (int mt = 0; mt < 4; ++mt)
#pragma unroll
                for (int nt = 0; nt < 4; ++nt)
                    acc[mt][nt] = MFMA(a[mt], b[nt], acc[mt][nt]);
        }
    }
    __syncthreads();   // As/Bs dead for all waves; Ct reuse safe
    if (wsel == 2) {
        // V: bounce TRANSPOSED (Ct[feature][token]) then store to VT rows
#pragma unroll
        for (int mt = 0; mt < 4; ++mt)
#pragma unroll
            for (int nt = 0; nt < 4; ++nt)
#pragma unroll
                for (int r = 0; r < 4; ++r)
                    Ct[(wn * 64 + nt * 16 + lr) * 136 + wm * 64 + mt * 16 + g * 4 + r] =
                        f2bf(acc[mt][nt][r]);
        __syncthreads();
        const int bq = rowBase >> 11;
        const int tok0 = rowBase & 2047;
#pragma unroll
        for (int pp = 0; pp < 8; ++pp) {
            int colf = pp * 16 + (tid >> 4);       // feature within tile
            int tkb = (tid & 15) * 8;              // token block
            u16x8 v8 = *reinterpret_cast<const u16x8*>(&Ct[colf * 136 + tkb]);
            *reinterpret_cast<u16x8*>(
                &O[(size_t)bq * 2097152 + (size_t)(colBase + colf) * 2048 + tok0 + tkb]) = v8;
        }
    } else {
#pragma unroll
        for (int mt = 0; mt < 4; ++mt)
#pragma unroll
            for (int nt = 0; nt < 4; ++nt)
#pragma unroll
                for (int r = 0; r < 4; ++r)
                    Ct[(wm * 64 + mt * 16 + g * 4 + r) * 136 + wn * 64 + nt * 16 + lr] =
                        f2bf(acc[mt][nt][r]);
        __syncthreads();
#pragma unroll
        for (int pp = 0; pp < 8; ++pp) {
            int row = pp * 16 + (tid >> 4);
            int col = (tid & 15) * 8;
            u16x8 v8 = *reinterpret_cast<const u16x8*>(&Ct[row * 136 + col]);
            *reinterpret_cast<u16x8*>(&O[(size_t)(rowBase + row) * N + colBase + col]) = v8;
        }
    }
}

// ---- MFMA flash attention: K and V^T both staged via global_load_lds (pure DMA) ----
__global__ __launch_bounds__(512)
void attn_fwd(const unsigned short* __restrict__ Q, const unsigned short* __restrict__ Kb,
              const unsigned short* __restrict__ VT, const int* __restrict__ seff,
              unsigned short* __restrict__ AO)
{
    constexpr int S = 2048, C = 1024, Dh = 64;
    constexpr int PST = 64;
    constexpr float SCL = 0.125f * 1.44269504f;
    constexpr float FM  = 16.0f;
    constexpr float MSK = -1.0e30f;
    __shared__ unsigned short Kt[2][64 * 64];   // [buf][key][slot-swizzled d]
    __shared__ unsigned short Vt[2][64 * 64];   // [buf][d][slot-swizzled key]  (from V^T)
    __shared__ unsigned short Pt[8][16 * PST];
    const int tid = threadIdx.x;
    const int w = tid >> 6, lane = tid & 63;
    const int g = lane >> 4, lr = lane & 15;
    const int lin = blockIdx.x;
    const int hb = lin & 63, qt = lin >> 6;
    const int h = hb >> 2, b = hb & 3;
    const int qbase = qt * 128;
    const int qrow = qbase + w * 16 + lr;

    const int Sb = seff[b];
    const int ntiles = (Sb + 63) >> 6;

    const unsigned short* qptr = Q + (size_t)(b * S + qrow) * C + h * Dh;
    short8 qf[2];
    qf[0] = *reinterpret_cast<const short8*>(qptr + g * 8);
    qf[1] = *reinterpret_cast<const short8*>(qptr + 32 + g * 8);

    short8 ones;
#pragma unroll
    for (int j = 0; j < 8; ++j) ones[j] = (short)0x3F80;

    f32x4 o[4] = {};
    f32x4 lacc = {};

    const unsigned short* kg = Kb + (size_t)(b * S) * C + h * Dh;
    const unsigned short* vtg = VT + (size_t)b * 2097152 + (size_t)(h * Dh) * 2048;

    // K: chunk tid -> key=tid>>3, dblk=(tid&7)^(key&7)
    const int kk0 = tid >> 3;
    const int kd0 = ((tid & 7) ^ (kk0 & 7)) * 8;
    // V^T: chunk tid -> d=tid>>3, keyblk=(tid&7)^(d&7)
    const int vd = tid >> 3;
    const int vkb = ((tid & 7) ^ (vd & 7)) * 8;

    // ---- prologue: stage tile 0 (pure DMA) ----
    GLOAD_LDS16(kg + (size_t)kk0 * C + kd0, &Kt[0][(size_t)tid * 8]);
    GLOAD_LDS16(vtg + (size_t)vd * 2048 + vkb, &Vt[0][(size_t)tid * 8]);
    asm volatile("s_waitcnt vmcnt(0)" ::: "memory");
    __syncthreads();

    int cur = 0;
    for (int tt = 0; tt < ntiles; ++tt) {
        const int t = tt * 64;
        const bool hasNext = (tt + 1) < ntiles;
        if (hasNext) {
            const int tn = t + 64;
            GLOAD_LDS16(kg + (size_t)(tn + kk0) * C + kd0, &Kt[cur ^ 1][(size_t)tid * 8]);
            GLOAD_LDS16(vtg + (size_t)vd * 2048 + tn + vkb, &Vt[cur ^ 1][(size_t)tid * 8]);
        }
        // QK^T : C-layout [qrow=g*4+r][key=lr]
        f32x4 s[4];
        __builtin_amdgcn_s_setprio(1);
#pragma unroll
        for (int nt = 0; nt < 4; ++nt) {
            int key = nt * 16 + lr;
            f32x4 a = {};
#pragma unroll
            for (int c = 0; c < 2; ++c) {
                int dd = c * 32 + g * 8;
                short8 kf = *reinterpret_cast<const short8*>(
                    &Kt[cur][key * 64 + (((dd >> 3) ^ (key & 7)) << 3)]);
                a = MFMA(qf[c], kf, a);
            }
            s[nt] = a;
        }
        __builtin_amdgcn_s_setprio(0);
        float madd[4];
#pragma unroll
        for (int nt = 0; nt < 4; ++nt)
            madd[nt] = ((t + nt * 16 + lr) < Sb) ? -FM : MSK;
        unsigned short* Pw = Pt[w];
#pragma unroll
        for (int nt = 0; nt < 4; ++nt) {
            int k = nt * 16 + lr;
#pragma unroll
            for (int r = 0; r < 4; ++r) {
                float p = __builtin_amdgcn_exp2f(s[nt][r] * SCL + madd[nt]);
                int row = g * 4 + r;
                Pw[row * PST + ((((k >> 3) ^ (row & 7)) << 3) | (k & 7))] = f2bfr(p);
            }
        }
        asm volatile("s_waitcnt lgkmcnt(0)" ::: "memory");
        __builtin_amdgcn_sched_barrier(0);
        short8 pf[2];
#pragma unroll
        for (int hh = 0; hh < 2; ++hh) {
            int kk = hh * 32 + g * 8;
            pf[hh] = *reinterpret_cast<const short8*>(
                &Pw[lr * PST + (((kk >> 3) ^ (lr & 7)) << 3)]);
        }
        // PV + MFMA row-sum; V frag from [d][key-swizzled] tile
        __builtin_amdgcn_s_setprio(1);
        lacc = MFMA(pf[0], ones, lacc);
        lacc = MFMA(pf[1], ones, lacc);
#pragma unroll
        for (int dt = 0; dt < 4; ++dt) {
            int d = dt * 16 + lr;
#pragma unroll
            for (int hh = 0; hh < 2; ++hh) {
                int kk = hh * 32 + g * 8;
                short8 vf = *reinterpret_cast<const short8*>(
                    &Vt[cur][d * 64 + ((((kk >> 3) ^ (d & 7)) << 3))]);
                o[dt] = MFMA(pf[hh], vf, o[dt]);
            }
        }
        __builtin_amdgcn_s_setprio(0);
        if (hasNext) asm volatile("s_waitcnt vmcnt(0)" ::: "memory");
        __syncthreads();
        cur ^= 1;
    }
#pragma unroll
    for (int dt = 0; dt < 4; ++dt)
#pragma unroll
        for (int r = 0; r < 4; ++r) {
            int row = qbase + w * 16 + g * 4 + r;
            int col = h * Dh + dt * 16 + lr;
            AO[(size_t)(b * S + row) * C + col] = f2bf(o[dt][r] / lacc[r]);
        }
}

// ---- Epilogue: LN with wave-shuffle reduction (r30-verified, unchanged) ----
__global__ __launch_bounds__(256)
void ln_ep(const unsigned short* __restrict__ AO, const unsigned short* __restrict__ R,
           const float* __restrict__ gamma, const float* __restrict__ beta,
           float* __restrict__ out)
{
    constexpr int C = 1024;
    const int row = blockIdx.x;
    const int tid = threadIdx.x;
    __shared__ float red[4][2];

    float v[4]; float sum = 0.f, ss = 0.f;
    u16x4 av = *reinterpret_cast<const u16x4*>(AO + (size_t)row * C + tid * 4);
    u16x4 rv = *reinterpret_cast<const u16x4*>(R + (size_t)row * C + tid * 4);
#pragma unroll
    for (int i = 0; i < 4; ++i) {
        v[i] = fmaxf(0.f, bf2f(av[i]) + bf2f(rv[i]));
        sum += v[i]; ss += v[i] * v[i];
    }
#pragma unroll
    for (int off = 1; off < 64; off <<= 1) {
        sum += __shfl_xor(sum, off, 64);
        ss += __shfl_xor(ss, off, 64);
    }
    int w = tid >> 6;
    if ((tid & 63) == 0) { red[w][0] = sum; red[w][1] = ss; }
    __syncthreads();
    sum = red[0][0] + red[1][0] + red[2][0] + red[3][0];
    ss = red[0][1] + red[1][1] + red[2][1] + red[3][1];
    float mu = sum * (1.f / C);
    float var = ss * (1.f / C) - mu * mu;
    float rstd = rsqrtf(var + 1e-5f);
    float4v g4 = *reinterpret_cast<const float4v*>(gamma + tid * 4);
    float4v b4 = *reinterpret_cast<const float4v*>(beta + tid * 4);
    float4v ov;
#pragma unroll
    for (int i = 0; i < 4; ++i)
        ov[i] = (v[i] - mu) * rstd * g4[i] + b4[i];
    *reinterpret_cast<float4v*>(out + (size_t)row * C + tid * 4) = ov;
}

extern "C" void kernel_launch(void* const* d_in, const int* in_sizes, int n_in,
                              void* d_out, int out_size, void* d_ws, size_t ws_size,
                              hipStream_t stream)
{
    const float* X = (const float*)d_in[0];
    const int* mask = (const int*)d_in[1];
    const float* Wq = (const float*)d_in[2];
    const float* Wk = (const float*)d_in[3];
    const float* Wv = (const float*)d_in[4];
    const float* Wr = (const float*)d_in[5];
    const float* Gm = (const float*)d_in[6];
    const float* Bt = (const float*)d_in[7];
    float* out = (float*)d_out;

    const size_t NE = (size_t)8192 * 1024;
    const size_t WE = (size_t)1024 * 1024;
    unsigned short* p = (unsigned short*)d_ws;
    unsigned short* Xb = p;   p += NE;
    unsigned short* Wqb = p;  p += WE;
    unsigned short* Wkb = p;  p += WE;
    unsigned short* Wvb = p;  p += WE;
    unsigned short* Wrb = p;  p += WE;
    unsigned short* Qb = p;   p += NE;
    unsigned short* Kb = p;   p += NE;
    unsigned short* VTb = p;  p += NE;   // V^T [b][feature 1024][token 2048]
    unsigned short* Rb = p;   p += NE;
    int* kidx = (int*)p;      p += 8192 * 2;
    int* seff = (int*)p;      p += 8;
    unsigned short* AO = Xb;  // alias: X dead after proj_gemm

    mask_scan<<<dim3(4), 256, 0, stream>>>(mask, kidx, seff);
    ingest_all<<<dim3(2048), 256, 0, stream>>>(X, Wq, Wk, Wv, Wr, Xb);

    proj_gemm<<<dim3(2304), 256, 0, stream>>>(Xb, Wqb, Wkb, Wvb, Wrb,
                                              Qb, Kb, VTb, Rb, kidx, seff);
    attn_fwd<<<dim3(1024), 512, 0, stream>>>(Qb, Kb, VTb, seff, AO);
    ln_ep<<<dim3(8192), 256, 0, stream>>>(AO, Rb, Gm, Bt, out);
}